// Round 2
// baseline (655.641 us; speedup 1.0000x reference)
//
#include <hip/hip_runtime.h>
#include <hip/hip_bf16.h>

// Encoder layer. Inputs/outputs fp32 (per reference dtypes); internal compute bf16 MFMA, fp32 accum.
// B=16 S=512 H=768 A=12 DH=64 F=3072. All GEMM dims multiples of 64 -> no bounds checks.

using bf16_t = __hip_bfloat16;
typedef __bf16 bf16x8 __attribute__((ext_vector_type(8)));
typedef float f32x4 __attribute__((ext_vector_type(4)));

__device__ __forceinline__ float b2f(bf16_t v) { return __bfloat162float(v); }
__device__ __forceinline__ bf16_t f2b(float v) { return __float2bfloat16(v); }

// ---------------------------------------------------------------------------
// fp32 -> bf16 elementwise cast (8 elems/thread)
// ---------------------------------------------------------------------------
__global__ __launch_bounds__(256) void cast_f32_bf16(
    const float* __restrict__ in, bf16_t* __restrict__ out)
{
    size_t i = ((size_t)blockIdx.x * 256 + threadIdx.x) * 8;
    float4 a = *(const float4*)(in + i);
    float4 b = *(const float4*)(in + i + 4);
#pragma unroll
    for (int j = 0; j < 4; ++j) {
        out[i + j]     = f2b(((const float*)&a)[j]);
        out[i + 4 + j] = f2b(((const float*)&b)[j]);
    }
}

// ---------------------------------------------------------------------------
// fp32 [R][C] -> bf16 [C][R] transpose+cast, 64x64 LDS tiles (weights, once/launch)
// ---------------------------------------------------------------------------
__global__ __launch_bounds__(256) void transpose_cast(
    const float* __restrict__ in, bf16_t* __restrict__ out, int R, int C)
{
    __shared__ float t[64][65];
    int r0 = blockIdx.y * 64, c0 = blockIdx.x * 64;
    int tr = threadIdx.x >> 6;   // 0..3
    int tc = threadIdx.x & 63;   // 0..63
#pragma unroll 4
    for (int i = 0; i < 16; ++i) {
        int r = i * 4 + tr;
        t[r][tc] = in[(size_t)(r0 + r) * C + c0 + tc];
    }
    __syncthreads();
#pragma unroll 4
    for (int i = 0; i < 16; ++i) {
        int r = i * 4 + tr;
        out[(size_t)(c0 + r) * R + r0 + tc] = f2b(t[tc][r]);
    }
}

// ---------------------------------------------------------------------------
// bf16 [R][C] -> bf16 [C][R] transpose, batched over blockIdx.z (per-head V)
// ---------------------------------------------------------------------------
__global__ __launch_bounds__(256) void transpose_bf(
    const ushort* __restrict__ in, ushort* __restrict__ out,
    int R, int C, long inB, long outB)
{
    __shared__ ushort t[64][65];
    const ushort* ip = in + (size_t)blockIdx.z * inB;
    ushort* op = out + (size_t)blockIdx.z * outB;
    int r0 = blockIdx.y * 64, c0 = blockIdx.x * 64;
    int tr = threadIdx.x >> 6;
    int tc = threadIdx.x & 63;
#pragma unroll 4
    for (int i = 0; i < 16; ++i) {
        int r = i * 4 + tr;
        t[r][tc] = ip[(size_t)(r0 + r) * C + c0 + tc];
    }
    __syncthreads();
#pragma unroll 4
    for (int i = 0; i < 16; ++i) {
        int r = i * 4 + tr;
        op[(size_t)(c0 + r) * R + r0 + tc] = t[tc][r];
    }
}

// ---------------------------------------------------------------------------
// NT GEMM: C[M,N] = A[M,K] @ Bt[N,K]^T (+ epilogue), bf16 in, fp32 acc.
// 64x64x32 tiles, 256 thr = 4 waves; wave w owns 16-col strip, 4 m-tiles.
// MFMA 16x16x32 bf16 (verified m89/m91 layouts):
//   A-frag A[m=lane&15][k=quad*8+j]; B-frag B[k=quad*8+j][n=lane&15]
//   C/D    col=lane&15, row=quad*4+reg
// EPI: 0 bias->bf16 | 1 bias+GELU->bf16 | 2 bias+res(fp32)->bf16
//      3 scores(*0.125,mask)->bf16 | 4 plain->bf16 | 5 bias+res(bf16)->fp32
// ---------------------------------------------------------------------------
template <int EPI>
__global__ __launch_bounds__(256) void gemm_nt(
    const bf16_t* __restrict__ A, const bf16_t* __restrict__ Bt,
    const float* __restrict__ bias, const void* __restrict__ res,
    const int* __restrict__ mask, void* __restrict__ Cv,
    int K, int lda, int ldb, int ldc,
    long strideAz, long strideBz, long strideCz)
{
    __shared__ ushort lA[64][40];  // +8 pad keeps 16B alignment, spreads banks
    __shared__ ushort lB[64][40];

    int z = blockIdx.z;
    A  += (size_t)z * strideAz;
    Bt += (size_t)z * strideBz;

    int m0 = blockIdx.x * 64, n0 = blockIdx.y * 64;
    int tid  = threadIdx.x;
    int lane = tid & 63, wave = tid >> 6;
    int l16 = lane & 15, quad = lane >> 4;
    int sr = tid >> 2;             // staging row 0..63
    int sc = (tid & 3) << 3;       // staging col 0,8,16,24

    f32x4 acc[4] = {{0.f,0.f,0.f,0.f},{0.f,0.f,0.f,0.f},{0.f,0.f,0.f,0.f},{0.f,0.f,0.f,0.f}};

    const ushort* ga = (const ushort*)A  + (size_t)(m0 + sr) * lda + sc;
    const ushort* gb = (const ushort*)Bt + (size_t)(n0 + sr) * ldb + sc;

    for (int k0 = 0; k0 < K; k0 += 32) {
        *(bf16x8*)&lA[sr][sc] = *(const bf16x8*)(ga + k0);
        *(bf16x8*)&lB[sr][sc] = *(const bf16x8*)(gb + k0);
        __syncthreads();
        bf16x8 bfr = *(const bf16x8*)&lB[wave * 16 + l16][quad * 8];
#pragma unroll
        for (int mi = 0; mi < 4; ++mi) {
            bf16x8 afr = *(const bf16x8*)&lA[mi * 16 + l16][quad * 8];
            acc[mi] = __builtin_amdgcn_mfma_f32_16x16x32_bf16(afr, bfr, acc[mi], 0, 0, 0);
        }
        __syncthreads();
    }

    int n = n0 + wave * 16 + l16;   // global col owned by this lane
    float bv = 0.f;
    if constexpr (EPI == 0 || EPI == 1 || EPI == 2 || EPI == 5) bv = bias[n];
    bool mz = false;
    if constexpr (EPI == 3) mz = (mask[(z / 12) * 512 + n] == 0);  // 12 heads/batch

#pragma unroll
    for (int mi = 0; mi < 4; ++mi) {
#pragma unroll
        for (int r = 0; r < 4; ++r) {
            int m = m0 + mi * 16 + quad * 4 + r;
            float v = acc[mi][r];
            if constexpr (EPI == 0) {
                v += bv;
            } else if constexpr (EPI == 1) {
                v += bv;
                v = 0.5f * v * (1.f + erff(v * 0.70710678118654752f));  // exact GELU
            } else if constexpr (EPI == 2) {
                v += bv + ((const float*)res)[(size_t)m * ldc + n];
            } else if constexpr (EPI == 3) {
                v *= 0.125f;                 // 1/sqrt(64)
                if (mz) v = -1e30f;
            } else if constexpr (EPI == 5) {
                v += bv + b2f(((const bf16_t*)res)[(size_t)m * ldc + n]);
            }
            if constexpr (EPI == 5) {
                float* C = (float*)Cv + (size_t)z * strideCz;
                C[(size_t)m * ldc + n] = v;
            } else {
                bf16_t* C = (bf16_t*)Cv + (size_t)z * strideCz;
                C[(size_t)m * ldc + n] = f2b(v);
            }
        }
    }
}

// ---------------------------------------------------------------------------
// Row softmax over 512-wide bf16 rows, one wave per row (4 rows / block).
// ---------------------------------------------------------------------------
__global__ __launch_bounds__(256) void softmax_kernel(bf16_t* __restrict__ P)
{
    int wave = threadIdx.x >> 6, lane = threadIdx.x & 63;
    bf16_t* p = P + ((size_t)blockIdx.x * 4 + wave) * 512;
    float v[8];
    float m = -3e38f;
#pragma unroll
    for (int i = 0; i < 8; ++i) { v[i] = b2f(p[lane + i * 64]); m = fmaxf(m, v[i]); }
#pragma unroll
    for (int off = 32; off; off >>= 1) m = fmaxf(m, __shfl_xor(m, off));
    float s = 0.f;
#pragma unroll
    for (int i = 0; i < 8; ++i) { v[i] = __expf(v[i] - m); s += v[i]; }
#pragma unroll
    for (int off = 32; off; off >>= 1) s += __shfl_xor(s, off);
    float inv = 1.f / s;
#pragma unroll
    for (int i = 0; i < 8; ++i) p[lane + i * 64] = f2b(v[i] * inv);
}

// ---------------------------------------------------------------------------
// LayerNorm over H=768, one block (256 thr) per row, fp32 stats. In-place safe.
// ---------------------------------------------------------------------------
__device__ __forceinline__ float to_f(float v)  { return v; }
__device__ __forceinline__ float to_f(bf16_t v) { return b2f(v); }
__device__ __forceinline__ void from_f(float& d, float v)  { d = v; }
__device__ __forceinline__ void from_f(bf16_t& d, float v) { d = f2b(v); }

template <typename TI, typename TO>
__global__ __launch_bounds__(256) void layernorm_kernel(
    const TI* __restrict__ X, const float* __restrict__ w,
    const float* __restrict__ b, TO* __restrict__ out)
{
    const TI* x = X + (size_t)blockIdx.x * 768;
    TO* o = out + (size_t)blockIdx.x * 768;
    int t = threadIdx.x;
    float v[3];
    float s = 0.f, sq = 0.f;
#pragma unroll
    for (int i = 0; i < 3; ++i) {
        v[i] = to_f(x[t + i * 256]);
        s += v[i]; sq += v[i] * v[i];
    }
#pragma unroll
    for (int off = 32; off; off >>= 1) { s += __shfl_xor(s, off); sq += __shfl_xor(sq, off); }
    __shared__ float s1[4], s2[4];
    int wave = t >> 6, lane = t & 63;
    if (lane == 0) { s1[wave] = s; s2[wave] = sq; }
    __syncthreads();
    s  = s1[0] + s1[1] + s1[2] + s1[3];
    sq = s2[0] + s2[1] + s2[2] + s2[3];
    float mu  = s * (1.f / 768.f);
    float var = sq * (1.f / 768.f) - mu * mu;
    float rs  = rsqrtf(var + 1e-5f);
#pragma unroll
    for (int i = 0; i < 3; ++i)
        from_f(o[t + i * 256], (v[i] - mu) * rs * w[t + i * 256] + b[t + i * 256]);
}

// ---------------------------------------------------------------------------
extern "C" void kernel_launch(void* const* d_in, const int* in_sizes, int n_in,
                              void* d_out, int out_size, void* d_ws, size_t ws_size,
                              hipStream_t stream)
{
    const float* X    = (const float*)d_in[0];
    const int*   mask = (const int*)  d_in[1];
    const float* WQ   = (const float*)d_in[2];
    const float* bQ   = (const float*)d_in[3];
    const float* WK   = (const float*)d_in[4];
    const float* bK   = (const float*)d_in[5];
    const float* WV   = (const float*)d_in[6];
    const float* bV   = (const float*)d_in[7];
    const float* WO   = (const float*)d_in[8];
    const float* bO   = (const float*)d_in[9];
    const float* ln1w = (const float*)d_in[10];
    const float* ln1b = (const float*)d_in[11];
    const float* W1   = (const float*)d_in[12];
    const float* b1   = (const float*)d_in[13];
    const float* W2   = (const float*)d_in[14];
    const float* b2   = (const float*)d_in[15];
    const float* ln2w = (const float*)d_in[16];
    const float* ln2b = (const float*)d_in[17];
    float* out = (float*)d_out;

    // ---- workspace layout (bf16 elems; total 39,321,600 elems = 75 MB) ----
    bf16_t* ws = (bf16_t*)d_ws;
    bf16_t* WQt = ws;                    // [768][768]
    bf16_t* WKt = WQt + 589824;
    bf16_t* WVt = WKt + 589824;
    bf16_t* WOt = WVt + 589824;
    bf16_t* W1t = WOt + 589824;          // [3072][768]
    bf16_t* W2t = W1t + 2359296;         // [768][3072]
    bf16_t* Vb  = W2t + 2359296;         // [8192][768] V projection (live through attn; X1 aliases after)
    bf16_t* Xb  = Vb  + 6291456;         // bf16 X (dead after QKV; Y1 aliases)
    bf16_t* Qb  = Xb  + 6291456;         // (Zb aliases per-group)
    bf16_t* Kb  = Qb  + 6291456;
    bf16_t* Vt  = Kb  + 6291456;         // per-group V^T: 2 batches = 786,432
    bf16_t* Pb  = Vt  + 786432;          // per-group scores: 24 heads x 512 x 512 = 6,291,456
    // aliases (dead-before-write):
    bf16_t* Zb = Qb;   // PV(g) overwrites Q(g) after scores(g) consumed it
    bf16_t* Y1 = Xb;   // Xb dead after QKV projections
    bf16_t* X1 = Vb;   // Vb dead after last per-group V transpose
    bf16_t* Hb = Xb;   // FFN mid [8192][3072] = 25,165,824 elems over Xb..Pb end (25,952,256) — all dead at FFN1

    // ---- 1. cast X, transpose+cast weights ----
    cast_f32_bf16<<<3072, 256, 0, stream>>>(X, Xb);                      // 6,291,456 / 8 / 256
    transpose_cast<<<dim3(12, 12), 256, 0, stream>>>(WQ, WQt, 768, 768);
    transpose_cast<<<dim3(12, 12), 256, 0, stream>>>(WK, WKt, 768, 768);
    transpose_cast<<<dim3(12, 12), 256, 0, stream>>>(WV, WVt, 768, 768);
    transpose_cast<<<dim3(12, 12), 256, 0, stream>>>(WO, WOt, 768, 768);
    transpose_cast<<<dim3(48, 12), 256, 0, stream>>>(W1, W1t, 768, 3072); // -> [3072][768]
    transpose_cast<<<dim3(12, 48), 256, 0, stream>>>(W2, W2t, 3072, 768); // -> [768][3072]

    // ---- 2. Q/K/V projections (M=8192, N=768, K=768) ----
    gemm_nt<0><<<dim3(128, 12), 256, 0, stream>>>(Xb, WQt, bQ, nullptr, nullptr, Qb, 768, 768, 768, 768, 0, 0, 0);
    gemm_nt<0><<<dim3(128, 12), 256, 0, stream>>>(Xb, WKt, bK, nullptr, nullptr, Kb, 768, 768, 768, 768, 0, 0, 0);
    gemm_nt<0><<<dim3(128, 12), 256, 0, stream>>>(Xb, WVt, bV, nullptr, nullptr, Vb, 768, 768, 768, 768, 0, 0, 0);

    // ---- 3. attention in groups of 2 batches (24 heads / group) ----
    // Faithful reshape (B,S,H)->(B,A,S,DH) is flat: head (b,a) = contiguous [512][64]
    // chunk at offset b*393216 + a*32768. z*32768 with z = b_in_group*12 + a covers it.
    for (int g = 0; g < 8; ++g) {
        const bf16_t* Qg = Qb + (size_t)g * 786432;
        const bf16_t* Kg = Kb + (size_t)g * 786432;
        const bf16_t* Vg = Vb + (size_t)g * 786432;
        bf16_t*       Zg = Zb + (size_t)g * 786432;
        const int* mg = mask + g * 1024;
        transpose_bf<<<dim3(1, 8, 24), 256, 0, stream>>>((const ushort*)Vg, (ushort*)Vt, 512, 64, 32768, 32768);
        gemm_nt<3><<<dim3(8, 8, 24), 256, 0, stream>>>(Qg, Kg, nullptr, nullptr, mg, Pb,
                                                       64, 64, 64, 512, 32768, 32768, 262144);
        softmax_kernel<<<3072, 256, 0, stream>>>(Pb);                    // 24*512 rows / 4
        gemm_nt<4><<<dim3(8, 1, 24), 256, 0, stream>>>(Pb, Vt, nullptr, nullptr, nullptr, Zg,
                                                       512, 512, 512, 64, 262144, 32768, 32768);
    }

    // ---- 4. O-projection + fp32 residual -> Y1, LN1 -> X1 ----
    gemm_nt<2><<<dim3(128, 12), 256, 0, stream>>>(Zb, WOt, bO, X, nullptr, Y1, 768, 768, 768, 768, 0, 0, 0);
    layernorm_kernel<bf16_t, bf16_t><<<8192, 256, 0, stream>>>(Y1, ln1w, ln1b, X1);

    // ---- 5. FFN: GELU(X1@W1+b1) -> Hb; Hb@W2+b2+X1 -> d_out (fp32); LN2 in-place ----
    gemm_nt<1><<<dim3(128, 48), 256, 0, stream>>>(X1, W1t, b1, nullptr, nullptr, Hb, 768, 768, 768, 3072, 0, 0, 0);
    gemm_nt<5><<<dim3(128, 12), 256, 0, stream>>>(Hb, W2t, b2, X1, nullptr, out, 3072, 3072, 3072, 768, 0, 0, 0);
    layernorm_kernel<float, float><<<8192, 256, 0, stream>>>(out, ln2w, ln2b, out);
}

// Round 3
// 444.811 us; speedup vs baseline: 1.4740x; 1.4740x over previous
//
#include <hip/hip_runtime.h>
#include <hip/hip_bf16.h>

// Encoder layer. fp32 in/out, bf16 MFMA compute, fp32 accum.
// B=16 S=512 H=768 A=12 DH=64 F=3072.
// Round 3: m97-class 128x128 GEMM (global_load_lds w=16, XOR-swizzled LDS) +
// fused flash attention (online softmax, P via LDS C->A layout round-trip).

using bf16_t = __hip_bfloat16;
typedef __bf16 bf16x8 __attribute__((ext_vector_type(8)));
typedef float f32x4 __attribute__((ext_vector_type(4)));

__device__ __forceinline__ float b2f(bf16_t v) { return __bfloat162float(v); }
__device__ __forceinline__ bf16_t f2b(float v) { return __float2bfloat16(v); }
__device__ __forceinline__ ushort f2bu(float v) { bf16_t b = f2b(v); return *(ushort*)&b; }

// async global->LDS 16B copy. Per m104/m108: LDS dest = wave-uniform base + lane*16;
// our per-lane dest pointers are exactly base + lane*16 by construction.
__device__ __forceinline__ void glds16(const ushort* g, ushort* l) {
    __builtin_amdgcn_global_load_lds(
        (const __attribute__((address_space(1))) unsigned int*)g,
        (__attribute__((address_space(3))) unsigned int*)l, 16, 0, 0);
}

// ---------------------------------------------------------------------------
// fp32 -> bf16 cast (8 elems/thread)
// ---------------------------------------------------------------------------
__global__ __launch_bounds__(256) void cast_f32_bf16(
    const float* __restrict__ in, bf16_t* __restrict__ out)
{
    size_t i = ((size_t)blockIdx.x * 256 + threadIdx.x) * 8;
    float4 a = *(const float4*)(in + i);
    float4 b = *(const float4*)(in + i + 4);
#pragma unroll
    for (int j = 0; j < 4; ++j) {
        out[i + j]     = f2b(((const float*)&a)[j]);
        out[i + 4 + j] = f2b(((const float*)&b)[j]);
    }
}

// ---------------------------------------------------------------------------
// fp32 [R][C] -> bf16 [C][R] transpose+cast (weights, once/launch)
// ---------------------------------------------------------------------------
__global__ __launch_bounds__(256) void transpose_cast(
    const float* __restrict__ in, bf16_t* __restrict__ out, int R, int C)
{
    __shared__ float t[64][65];
    int r0 = blockIdx.y * 64, c0 = blockIdx.x * 64;
    int tr = threadIdx.x >> 6, tc = threadIdx.x & 63;
#pragma unroll 4
    for (int i = 0; i < 16; ++i) {
        int r = i * 4 + tr;
        t[r][tc] = in[(size_t)(r0 + r) * C + c0 + tc];
    }
    __syncthreads();
#pragma unroll 4
    for (int i = 0; i < 16; ++i) {
        int r = i * 4 + tr;
        out[(size_t)(c0 + r) * R + r0 + tc] = f2b(t[tc][r]);
    }
}

// ---------------------------------------------------------------------------
// bf16 [R][C] -> bf16 [C][R] transpose, batched over z (per-head V)
// ---------------------------------------------------------------------------
__global__ __launch_bounds__(256) void transpose_bf(
    const ushort* __restrict__ in, ushort* __restrict__ out,
    int R, int C, long inB, long outB)
{
    __shared__ ushort t[64][65];
    const ushort* ip = in + (size_t)blockIdx.z * inB;
    ushort* op = out + (size_t)blockIdx.z * outB;
    int r0 = blockIdx.y * 64, c0 = blockIdx.x * 64;
    int tr = threadIdx.x >> 6, tc = threadIdx.x & 63;
#pragma unroll 4
    for (int i = 0; i < 16; ++i) {
        int r = i * 4 + tr;
        t[r][tc] = ip[(size_t)(r0 + r) * C + c0 + tc];
    }
    __syncthreads();
#pragma unroll 4
    for (int i = 0; i < 16; ++i) {
        int r = i * 4 + tr;
        op[(size_t)(c0 + r) * R + r0 + tc] = t[tc][r];
    }
}

// ---------------------------------------------------------------------------
// m97-class NT GEMM: C[M,N] = A[M,K] @ Bt[N,K]^T (+ epilogue).
// 128x128x32 tiles, 256 thr = 4 waves; wave w -> 64x64 quadrant (wm=w&1, wn=w>>1),
// 4x4 MFMA 16x16x32 accs. Staging via global_load_lds width=16 into unpadded
// [128][32] LDS with XOR chunk swizzle phys = logical ^ ((row>>1)&3):
//   - staging dest for thread t = lX + t*16B (wave-contiguous, required by glds)
//   - frag reads land 2 lanes/bank (free per m136)
// EPI: 0 bias->bf16 | 1 bias+exact GELU->bf16 | 2 bias+res(fp32)->bf16 | 5 bias+res(bf16)->fp32
// ---------------------------------------------------------------------------
template <int EPI>
__global__ __launch_bounds__(256) void gemm128(
    const bf16_t* __restrict__ A, const bf16_t* __restrict__ Bt,
    const float* __restrict__ bias, const void* __restrict__ res,
    void* __restrict__ Cv, int K, int lda, int ldb, int ldc)
{
    __shared__ ushort lA[128 * 32];
    __shared__ ushort lB[128 * 32];
    const int tid = threadIdx.x;
    const int l = tid & 63, w = tid >> 6;
    const int l16 = l & 15, quad = l >> 4;
    const int m0 = blockIdx.x * 128, n0 = blockIdx.y * 128;

    // staging: thread t -> row tid>>2 (and +64), phys chunk tid&3, logical col swizzled
    const int srow = tid >> 2;
    const int scol = (((tid & 3) ^ ((tid >> 3) & 3)) << 3);
    const ushort* gA = (const ushort*)A + (size_t)(m0 + srow) * lda + scol;
    const ushort* gB = (const ushort*)Bt + (size_t)(n0 + srow) * ldb + scol;
    const size_t skipA = (size_t)64 * lda, skipB = (size_t)64 * ldb;
    ushort* dA = lA + tid * 8;
    ushort* dB = lB + tid * 8;

    f32x4 acc[4][4] = {};
    const int arow = (w & 1) * 64;
    const int brow = (w >> 1) * 64;
    const int pch = ((quad ^ ((l16 >> 1) & 3)) << 3);  // physical chunk (elems)

    for (int k0 = 0; k0 < K; k0 += 32) {
        __syncthreads();                       // prev-iter LDS reads done
        glds16(gA + k0,         dA);
        glds16(gA + k0 + skipA, dA + 2048);
        glds16(gB + k0,         dB);
        glds16(gB + k0 + skipB, dB + 2048);
        __syncthreads();                       // staging drained (vmcnt0 before barrier)
        bf16x8 bfr[4];
#pragma unroll
        for (int ni = 0; ni < 4; ++ni)
            bfr[ni] = *(const bf16x8*)&lB[(brow + ni * 16 + l16) * 32 + pch];
#pragma unroll
        for (int mi = 0; mi < 4; ++mi) {
            bf16x8 afr = *(const bf16x8*)&lA[(arow + mi * 16 + l16) * 32 + pch];
#pragma unroll
            for (int ni = 0; ni < 4; ++ni)
                acc[mi][ni] = __builtin_amdgcn_mfma_f32_16x16x32_bf16(afr, bfr[ni], acc[mi][ni], 0, 0, 0);
        }
    }

    float bv[4];
#pragma unroll
    for (int ni = 0; ni < 4; ++ni) bv[ni] = bias ? bias[n0 + brow + ni * 16 + l16] : 0.f;

#pragma unroll
    for (int mi = 0; mi < 4; ++mi) {
#pragma unroll
        for (int ni = 0; ni < 4; ++ni) {
            int n = n0 + brow + ni * 16 + l16;
#pragma unroll
            for (int r = 0; r < 4; ++r) {
                int m = m0 + arow + mi * 16 + quad * 4 + r;
                float v = acc[mi][ni][r] + bv[ni];
                if constexpr (EPI == 1) {
                    v = 0.5f * v * (1.f + erff(v * 0.70710678118654752f));  // exact GELU
                } else if constexpr (EPI == 2) {
                    v += ((const float*)res)[(size_t)m * ldc + n];
                } else if constexpr (EPI == 5) {
                    v += b2f(((const bf16_t*)res)[(size_t)m * ldc + n]);
                }
                if constexpr (EPI == 5) {
                    ((float*)Cv)[(size_t)m * ldc + n] = v;
                } else {
                    ((bf16_t*)Cv)[(size_t)m * ldc + n] = f2b(v);
                }
            }
        }
    }
}

// ---------------------------------------------------------------------------
// Flash attention: one block = (q-tile 64, head). S=512, D=64, 8 K-tiles.
// S-tile = Q @ K^T (MFMA, C-layout) -> online softmax -> P via LDS (C->A layout)
// -> P @ V^T-tile (MFMA) accumulate O. V pre-transposed per head ([64][512]).
// lK/lV staged via global_load_lds with XOR swizzle phys8 = log8 ^ (row&7).
// Z written in-place over Q (each block reads only its own Q rows, first).
// ---------------------------------------------------------------------------
__global__ __launch_bounds__(256) void flash_kernel(
    const bf16_t* __restrict__ Q, const bf16_t* __restrict__ Kx,
    const bf16_t* __restrict__ Vt, const int* __restrict__ mask,
    bf16_t* __restrict__ Z)
{
    __shared__ ushort lK[64 * 64];   // [s][d], 128B rows, swizzled chunks
    __shared__ ushort lV[64 * 64];   // [d][s], 128B rows, swizzled chunks
    __shared__ ushort lP[64 * 72];   // padded stride 72 (16B-aligned rows)

    const int h = blockIdx.y;                 // b*12 + a
    const int q0 = blockIdx.x * 64;
    const ushort* Qh = (const ushort*)Q + (size_t)h * 32768;
    const ushort* Kh = (const ushort*)Kx + (size_t)h * 32768;
    const ushort* Vh = (const ushort*)Vt + (size_t)h * 32768;   // [64][512]
    const int* mk = mask + (h / 12) * 512;
    ushort* Zh = (ushort*)Z + (size_t)h * 32768;

    const int tid = threadIdx.x;
    const int l = tid & 63, w = tid >> 6;
    const int l16 = l & 15, quad = l >> 4;

    // Q fragments (A-layout): rows q0 + w*16 + l16, k = kk*32 + quad*8
    bf16x8 qfr[2];
#pragma unroll
    for (int kk = 0; kk < 2; ++kk)
        qfr[kk] = *(const bf16x8*)(Qh + (size_t)(q0 + w * 16 + l16) * 64 + kk * 32 + quad * 8);

    // staging indices: chunk = p*256 + tid; row = chunk>>3; phys c8 = chunk&7
    const int c8p = tid & 7;
    const int kr0 = tid >> 3;            // rows 0..31 (pass 0), +32 (pass 1)
    float m_i[4] = {-1e30f, -1e30f, -1e30f, -1e30f};
    float l_i[4] = {0.f, 0.f, 0.f, 0.f};
    f32x4 o4[4] = {};

    const int sw = (quad << 2);          // logical chunk base per quad: kk*4+quad

    for (int kt = 0; kt < 8; ++kt) {
        // stage K-tile (contiguous 8KB) and Vt-tile ([64][512] rows, 64-col slice)
#pragma unroll
        for (int p = 0; p < 2; ++p) {
            int row = kr0 + p * 32;
            int c8l = c8p ^ (row & 7);
            glds16(Kh + (size_t)(kt * 64 + row) * 64 + c8l * 8, lK + (p * 256 + tid) * 8);
            glds16(Vh + (size_t)row * 512 + kt * 64 + c8l * 8, lV + (p * 256 + tid) * 8);
        }
        __syncthreads();                 // staging drained

        // S = Q @ K^T  (C-layout: row = quad*4+r within wave strip, col = ntile*16+l16)
        f32x4 s4[4] = {};
#pragma unroll
        for (int kk = 0; kk < 2; ++kk) {
#pragma unroll
            for (int nt = 0; nt < 4; ++nt) {
                int rr = nt * 16 + l16;
                bf16x8 bfr = *(const bf16x8*)&lK[rr * 64 + (((kk * 4 + quad) ^ (l16 & 7)) << 3)];
                s4[nt] = __builtin_amdgcn_mfma_f32_16x16x32_bf16(qfr[kk], bfr, s4[nt], 0, 0, 0);
            }
        }

        // online softmax over this 64-col tile
        bool mz[4];
#pragma unroll
        for (int nt = 0; nt < 4; ++nt) mz[nt] = (mk[kt * 64 + nt * 16 + l16] == 0);
        float pv[4][4];
#pragma unroll
        for (int r = 0; r < 4; ++r) {
            float rm = -1e30f;
#pragma unroll
            for (int nt = 0; nt < 4; ++nt) {
                float v = mz[nt] ? -1e30f : s4[nt][r] * 0.125f;
                pv[nt][r] = v;
                rm = fmaxf(rm, v);
            }
#pragma unroll
            for (int off = 1; off < 16; off <<= 1) rm = fmaxf(rm, __shfl_xor(rm, off));
            float mn = fmaxf(m_i[r], rm);
            float al = __expf(m_i[r] - mn);
            float rs = 0.f;
#pragma unroll
            for (int nt = 0; nt < 4; ++nt) {
                float e = __expf(pv[nt][r] - mn);
                pv[nt][r] = e;
                rs += e;
            }
#pragma unroll
            for (int off = 1; off < 16; off <<= 1) rs += __shfl_xor(rs, off);
            l_i[r] = l_i[r] * al + rs;
            m_i[r] = mn;
#pragma unroll
            for (int dt = 0; dt < 4; ++dt) o4[dt][r] *= al;
        }

        // P: C-layout -> LDS (A-layout source for PV)
#pragma unroll
        for (int nt = 0; nt < 4; ++nt)
#pragma unroll
            for (int r = 0; r < 4; ++r)
                lP[(w * 16 + quad * 4 + r) * 72 + nt * 16 + l16] = f2bu(pv[nt][r]);
        __syncthreads();                 // P visible; lK reads done

        // O += P @ V^T-tile
#pragma unroll
        for (int kk = 0; kk < 2; ++kk) {
            bf16x8 pafr = *(const bf16x8*)&lP[(w * 16 + l16) * 72 + kk * 32 + quad * 8];
#pragma unroll
            for (int dt = 0; dt < 4; ++dt) {
                bf16x8 bvfr = *(const bf16x8*)&lV[(dt * 16 + l16) * 64 + (((kk * 4 + quad) ^ (l16 & 7)) << 3)];
                o4[dt] = __builtin_amdgcn_mfma_f32_16x16x32_bf16(pafr, bvfr, o4[dt], 0, 0, 0);
            }
        }
        __syncthreads();                 // lV/lP reads done before next staging
    }

    // normalize + write Z (in-place over Q)
    float inv[4];
#pragma unroll
    for (int r = 0; r < 4; ++r) inv[r] = 1.f / l_i[r];
#pragma unroll
    for (int dt = 0; dt < 4; ++dt)
#pragma unroll
        for (int r = 0; r < 4; ++r)
            Zh[(size_t)(q0 + w * 16 + quad * 4 + r) * 64 + dt * 16 + l16] = f2bu(o4[dt][r] * inv[r]);
}

// ---------------------------------------------------------------------------
// LayerNorm over H=768, one block per row, fp32 stats. In-place safe.
// ---------------------------------------------------------------------------
__device__ __forceinline__ float to_f(float v)  { return v; }
__device__ __forceinline__ float to_f(bf16_t v) { return b2f(v); }
__device__ __forceinline__ void from_f(float& d, float v)  { d = v; }
__device__ __forceinline__ void from_f(bf16_t& d, float v) { d = f2b(v); }

template <typename TI, typename TO>
__global__ __launch_bounds__(256) void layernorm_kernel(
    const TI* __restrict__ X, const float* __restrict__ w,
    const float* __restrict__ b, TO* __restrict__ out)
{
    const TI* x = X + (size_t)blockIdx.x * 768;
    TO* o = out + (size_t)blockIdx.x * 768;
    int t = threadIdx.x;
    float v[3];
    float s = 0.f, sq = 0.f;
#pragma unroll
    for (int i = 0; i < 3; ++i) {
        v[i] = to_f(x[t + i * 256]);
        s += v[i]; sq += v[i] * v[i];
    }
#pragma unroll
    for (int off = 32; off; off >>= 1) { s += __shfl_xor(s, off); sq += __shfl_xor(sq, off); }
    __shared__ float s1[4], s2[4];
    int wave = t >> 6, lane = t & 63;
    if (lane == 0) { s1[wave] = s; s2[wave] = sq; }
    __syncthreads();
    s  = s1[0] + s1[1] + s1[2] + s1[3];
    sq = s2[0] + s2[1] + s2[2] + s2[3];
    float mu  = s * (1.f / 768.f);
    float var = sq * (1.f / 768.f) - mu * mu;
    float rs  = rsqrtf(var + 1e-5f);
#pragma unroll
    for (int i = 0; i < 3; ++i)
        from_f(o[t + i * 256], (v[i] - mu) * rs * w[t + i * 256] + b[t + i * 256]);
}

// ---------------------------------------------------------------------------
extern "C" void kernel_launch(void* const* d_in, const int* in_sizes, int n_in,
                              void* d_out, int out_size, void* d_ws, size_t ws_size,
                              hipStream_t stream)
{
    const float* X    = (const float*)d_in[0];
    const int*   mask = (const int*)  d_in[1];
    const float* WQ   = (const float*)d_in[2];
    const float* bQ   = (const float*)d_in[3];
    const float* WK   = (const float*)d_in[4];
    const float* bK   = (const float*)d_in[5];
    const float* WV   = (const float*)d_in[6];
    const float* bV   = (const float*)d_in[7];
    const float* WO   = (const float*)d_in[8];
    const float* bO   = (const float*)d_in[9];
    const float* ln1w = (const float*)d_in[10];
    const float* ln1b = (const float*)d_in[11];
    const float* W1   = (const float*)d_in[12];
    const float* b1   = (const float*)d_in[13];
    const float* W2   = (const float*)d_in[14];
    const float* b2   = (const float*)d_in[15];
    const float* ln2w = (const float*)d_in[16];
    const float* ln2b = (const float*)d_in[17];
    float* out = (float*)d_out;

    // ---- workspace (bf16 elems; total 38,535,168 = 77.1 MB, < known-safe 78.6) ----
    bf16_t* ws = (bf16_t*)d_ws;
    bf16_t* WQt = ws;                      // [768][768]
    bf16_t* WKt = WQt + 589824;
    bf16_t* WVt = WKt + 589824;
    bf16_t* WOt = WVt + 589824;
    bf16_t* W1t = WOt + 589824;            // [3072][768]
    bf16_t* W2t = W1t + 2359296;           // [768][3072]
    bf16_t* Vb  = W2t + 2359296;           // V proj (X1 alias after flash)
    bf16_t* Xb  = Vb  + 6291456;           // bf16 X (Y1 alias; Hb starts here)
    bf16_t* Qb  = Xb  + 6291456;           // Q proj (Z written in-place by flash)
    bf16_t* Kb  = Qb  + 6291456;
    bf16_t* Vt  = Kb  + 6291456;           // per-head V^T [64][512]
    bf16_t* Zb = Qb;                       // flash output, in-place over Q
    bf16_t* Y1 = Xb;                       // Xb dead after QKV
    bf16_t* X1 = Vb;                       // Vb dead after V transpose + flash
    bf16_t* Hb = Xb;                       // FFN mid spans Xb+Qb+Kb+Vt = 25,165,824 (all dead)

    // ---- 1. cast X, transpose+cast weights ----
    cast_f32_bf16<<<3072, 256, 0, stream>>>(X, Xb);
    transpose_cast<<<dim3(12, 12), 256, 0, stream>>>(WQ, WQt, 768, 768);
    transpose_cast<<<dim3(12, 12), 256, 0, stream>>>(WK, WKt, 768, 768);
    transpose_cast<<<dim3(12, 12), 256, 0, stream>>>(WV, WVt, 768, 768);
    transpose_cast<<<dim3(12, 12), 256, 0, stream>>>(WO, WOt, 768, 768);
    transpose_cast<<<dim3(48, 12), 256, 0, stream>>>(W1, W1t, 768, 3072);
    transpose_cast<<<dim3(12, 48), 256, 0, stream>>>(W2, W2t, 3072, 768);

    // ---- 2. Q/K/V projections (M=8192, N=768, K=768) ----
    gemm128<0><<<dim3(64, 6), 256, 0, stream>>>(Xb, WQt, bQ, nullptr, Qb, 768, 768, 768, 768);
    gemm128<0><<<dim3(64, 6), 256, 0, stream>>>(Xb, WKt, bK, nullptr, Kb, 768, 768, 768, 768);
    gemm128<0><<<dim3(64, 6), 256, 0, stream>>>(Xb, WVt, bV, nullptr, Vb, 768, 768, 768, 768);

    // ---- 3. per-head V transpose [512][64] -> [64][512], all 192 heads ----
    transpose_bf<<<dim3(1, 8, 192), 256, 0, stream>>>((const ushort*)Vb, (ushort*)Vt, 512, 64, 32768, 32768);

    // ---- 4. fused flash attention, all heads, Z in-place over Q ----
    flash_kernel<<<dim3(8, 192), 256, 0, stream>>>(Qb, Kb, Vt, mask, Zb);

    // ---- 5. O-projection + fp32 residual -> Y1, LN1 -> X1 ----
    gemm128<2><<<dim3(64, 6), 256, 0, stream>>>(Zb, WOt, bO, X, Y1, 768, 768, 768, 768);
    layernorm_kernel<bf16_t, bf16_t><<<8192, 256, 0, stream>>>(Y1, ln1w, ln1b, X1);

    // ---- 6. FFN: GELU(X1@W1+b1) -> Hb; Hb@W2+b2+X1 -> out (fp32); LN2 in-place ----
    gemm128<1><<<dim3(64, 24), 256, 0, stream>>>(X1, W1t, b1, nullptr, Hb, 768, 768, 768, 3072);
    gemm128<5><<<dim3(64, 6), 256, 0, stream>>>(Hb, W2t, b2, X1, out, 3072, 3072, 3072, 768);
    layernorm_kernel<float, float><<<8192, 256, 0, stream>>>(out, ln2w, ln2b, out);
}

// Round 5
// 394.196 us; speedup vs baseline: 1.6632x; 1.1284x over previous
//
#include <hip/hip_runtime.h>
#include <hip/hip_bf16.h>

// Encoder layer. fp32 in/out, bf16 MFMA compute, fp32 accum.
// B=16 S=512 H=768 A=12 DH=64 F=3072.
// Round 5: fused QKV gemm with SEGMENTED epilogue -> packed Q/K/V buffers
// (the faithful reshape (B,S,H)->(B,A,S,DH) is a flat reinterpretation:
//  head (b,a) = contiguous 32768-elem slice of the PACKED per-matrix buffer;
//  round 4's strided-column layout was the (B,S,A,DH) reshape = wrong op).
// Keeps: NTILE=64 gemm for N=768 outputs, prep mega-kernel, flash attention.

using bf16_t = __hip_bfloat16;
typedef __bf16 bf16x8 __attribute__((ext_vector_type(8)));
typedef float f32x4 __attribute__((ext_vector_type(4)));

__device__ __forceinline__ float b2f(bf16_t v) { return __bfloat162float(v); }
__device__ __forceinline__ bf16_t f2b(float v) { return __float2bfloat16(v); }
__device__ __forceinline__ ushort f2bu(float v) { bf16_t b = f2b(v); return *(ushort*)&b; }

// async global->LDS 16B copy (dest = wave base + lane*16 by construction)
__device__ __forceinline__ void glds16(const ushort* g, ushort* l) {
    __builtin_amdgcn_global_load_lds(
        (const __attribute__((address_space(1))) unsigned int*)g,
        (__attribute__((address_space(3))) unsigned int*)l, 16, 0, 0);
}

// ---------------------------------------------------------------------------
// Prep mega-kernel: 6 weight transposes (fp32 [R][C] -> bf16 [C][R]) + bias
// concat (bQ|bK|bV -> bcat fp32[2304]) + X cast. One launch.
// ---------------------------------------------------------------------------
__device__ __forceinline__ void tr_tile(const float* __restrict__ in,
                                        bf16_t* __restrict__ out,
                                        int R, int C, int tx, int ty,
                                        float (*t)[65], int tid)
{
    int r0 = ty * 64, c0 = tx * 64;
    int tr = tid >> 6, tc = tid & 63;
#pragma unroll 4
    for (int i = 0; i < 16; ++i) {
        int r = i * 4 + tr;
        t[r][tc] = in[(size_t)(r0 + r) * C + c0 + tc];
    }
    __syncthreads();
#pragma unroll 4
    for (int i = 0; i < 16; ++i) {
        int r = i * 4 + tr;
        out[(size_t)(c0 + r) * R + r0 + tc] = f2b(t[tc][r]);
    }
}

__global__ __launch_bounds__(256) void prep_kernel(
    const float* __restrict__ WQ, const float* __restrict__ WK,
    const float* __restrict__ WV, const float* __restrict__ WO,
    const float* __restrict__ W1, const float* __restrict__ W2,
    const float* __restrict__ bQ, const float* __restrict__ bK,
    const float* __restrict__ bV, const float* __restrict__ X,
    bf16_t* __restrict__ Wqkv, bf16_t* __restrict__ WOt,
    bf16_t* __restrict__ W1t, bf16_t* __restrict__ W2t,
    float* __restrict__ bcat, bf16_t* __restrict__ Xb)
{
    __shared__ float t[64][65];
    const int blk = blockIdx.x, tid = threadIdx.x;
    if (blk < 576) {                       // 768x768 transposes
        int m = blk / 144, tt = blk % 144;
        const float* in = (m == 0) ? WQ : (m == 1) ? WK : (m == 2) ? WV : WO;
        bf16_t* out = (m == 0) ? Wqkv : (m == 1) ? Wqkv + 589824
                    : (m == 2) ? Wqkv + 1179648 : WOt;
        tr_tile(in, out, 768, 768, tt % 12, tt / 12, t, tid);
    } else if (blk < 1152) {               // W1 [768][3072] -> [3072][768]
        int tt = blk - 576;
        tr_tile(W1, W1t, 768, 3072, tt % 48, tt / 48, t, tid);
    } else if (blk < 1728) {               // W2 [3072][768] -> [768][3072]
        int tt = blk - 1152;
        tr_tile(W2, W2t, 3072, 768, tt % 12, tt / 12, t, tid);
    } else if (blk == 1728) {              // bias concat
        for (int i = tid; i < 2304; i += 256)
            bcat[i] = (i < 768) ? bQ[i] : (i < 1536) ? bK[i - 768] : bV[i - 1536];
    } else {                               // X cast, 2048 elems/block
        size_t i = ((size_t)(blk - 1729) * 256 + tid) * 8;
        float4 a = *(const float4*)(X + i);
        float4 b = *(const float4*)(X + i + 4);
#pragma unroll
        for (int j = 0; j < 4; ++j) {
            Xb[i + j]     = f2b(((const float*)&a)[j]);
            Xb[i + 4 + j] = f2b(((const float*)&b)[j]);
        }
    }
}

// ---------------------------------------------------------------------------
// bf16 [R][C] -> bf16 [C][R] transpose, batched over z (per-head V, packed)
// ---------------------------------------------------------------------------
__global__ __launch_bounds__(256) void transpose_bf(
    const ushort* __restrict__ in, ushort* __restrict__ out,
    int R, int C, long inB, long outB)
{
    __shared__ ushort t[64][65];
    const ushort* ip = in + (size_t)blockIdx.z * inB;
    ushort* op = out + (size_t)blockIdx.z * outB;
    int r0 = blockIdx.y * 64, c0 = blockIdx.x * 64;
    int tr = threadIdx.x >> 6, tc = threadIdx.x & 63;
#pragma unroll 4
    for (int i = 0; i < 16; ++i) {
        int r = i * 4 + tr;
        t[r][tc] = ip[(size_t)(r0 + r) * C + c0 + tc];
    }
    __syncthreads();
#pragma unroll 4
    for (int i = 0; i < 16; ++i) {
        int r = i * 4 + tr;
        op[(size_t)(c0 + r) * R + r0 + tc] = t[tc][r];
    }
}

// ---------------------------------------------------------------------------
// m97-class NT GEMM: C[M,N] = A[M,K] @ Bt[N,K]^T (+ epilogue).
// Tile 128 x NTILE x 32 (NTILE 128 or 64), 256 thr = 4 waves.
// Staging via global_load_lds w=16, unpadded LDS, XOR chunk swizzle
// phys = logical ^ ((row>>1)&3) -> 2 lanes/bank frag reads (free, m136).
// EPI: 0 bias->bf16 | 1 bias+exact GELU->bf16 | 2 bias+res(fp32,ld=ldc)->bf16
//      5 bias+res(bf16,ld=ldc)->fp32 | 6 bias, segmented n/768 -> packed bufs
// ---------------------------------------------------------------------------
template <int EPI, int NTILE>
__global__ __launch_bounds__(256) void gemm128(
    const bf16_t* __restrict__ A, const bf16_t* __restrict__ Bt,
    const float* __restrict__ bias, const void* __restrict__ res,
    void* __restrict__ Cv, int K, int lda, int ldb, int ldc)
{
    __shared__ ushort lA[128 * 32];
    __shared__ ushort lB[NTILE * 32];
    constexpr int NI = NTILE / 32;
    const int tid = threadIdx.x;
    const int l = tid & 63, w = tid >> 6;
    const int l16 = l & 15, quad = l >> 4;
    const int m0 = blockIdx.x * 128, n0 = blockIdx.y * NTILE;

    const int srow = tid >> 2;
    const int scol = (((tid & 3) ^ ((tid >> 3) & 3)) << 3);
    const ushort* gA = (const ushort*)A + (size_t)(m0 + srow) * lda + scol;
    const ushort* gB = (const ushort*)Bt + (size_t)(n0 + srow) * ldb + scol;
    const size_t skipA = (size_t)64 * lda, skipB = (size_t)64 * ldb;
    ushort* dA = lA + tid * 8;
    ushort* dB = lB + tid * 8;

    f32x4 acc[4][NI] = {};
    const int arow = (w & 1) * 64;
    const int brow = (w >> 1) * (NTILE / 2);
    const int pch = ((quad ^ ((l16 >> 1) & 3)) << 3);

    for (int k0 = 0; k0 < K; k0 += 32) {
        __syncthreads();
        glds16(gA + k0,         dA);
        glds16(gA + k0 + skipA, dA + 2048);
        glds16(gB + k0,         dB);
        if constexpr (NTILE == 128) glds16(gB + k0 + skipB, dB + 2048);
        __syncthreads();
        bf16x8 bfr[NI];
#pragma unroll
        for (int ni = 0; ni < NI; ++ni)
            bfr[ni] = *(const bf16x8*)&lB[(brow + ni * 16 + l16) * 32 + pch];
#pragma unroll
        for (int mi = 0; mi < 4; ++mi) {
            bf16x8 afr = *(const bf16x8*)&lA[(arow + mi * 16 + l16) * 32 + pch];
#pragma unroll
            for (int ni = 0; ni < NI; ++ni)
                acc[mi][ni] = __builtin_amdgcn_mfma_f32_16x16x32_bf16(afr, bfr[ni], acc[mi][ni], 0, 0, 0);
        }
    }

    float bv[NI];
#pragma unroll
    for (int ni = 0; ni < NI; ++ni) bv[ni] = bias[n0 + brow + ni * 16 + l16];

    // EPI 6: each NTILE=128 n-tile lies wholly in one of Q/K/V (768 % 128 == 0);
    // rebase to the packed per-matrix buffer (faithful-reshape requirement).
    bf16_t* Cseg = nullptr;
    int nloc0 = 0;
    if constexpr (EPI == 6) {
        Cseg = (bf16_t*)Cv + (size_t)(n0 / 768) * 6291456;
        nloc0 = (n0 % 768) + brow;
    }

#pragma unroll
    for (int mi = 0; mi < 4; ++mi) {
#pragma unroll
        for (int ni = 0; ni < NI; ++ni) {
            int n = n0 + brow + ni * 16 + l16;
#pragma unroll
            for (int r = 0; r < 4; ++r) {
                int m = m0 + arow + mi * 16 + quad * 4 + r;
                float v = acc[mi][ni][r] + bv[ni];
                if constexpr (EPI == 1) {
                    v = 0.5f * v * (1.f + erff(v * 0.70710678118654752f));  // exact GELU
                } else if constexpr (EPI == 2) {
                    v += ((const float*)res)[(size_t)m * ldc + n];
                } else if constexpr (EPI == 5) {
                    v += b2f(((const bf16_t*)res)[(size_t)m * ldc + n]);
                }
                if constexpr (EPI == 5) {
                    ((float*)Cv)[(size_t)m * ldc + n] = v;
                } else if constexpr (EPI == 6) {
                    Cseg[(size_t)m * 768 + nloc0 + ni * 16 + l16] = f2b(v);
                } else {
                    ((bf16_t*)Cv)[(size_t)m * ldc + n] = f2b(v);
                }
            }
        }
    }
}

// ---------------------------------------------------------------------------
// Flash attention on PACKED per-matrix buffers: one block = (q-tile 64, head h).
// Head h = contiguous 32768-elem [512][64] slice (faithful flat reshape).
// S=512 D=64, 8 K-tiles; online softmax; P via padded LDS (C->A layout);
// V pre-transposed per head ([64][512]). Z in-place over Q.
// ---------------------------------------------------------------------------
__global__ __launch_bounds__(256) void flash_kernel(
    const bf16_t* __restrict__ Q, const bf16_t* __restrict__ Kx,
    const bf16_t* __restrict__ Vt, const int* __restrict__ mask,
    bf16_t* __restrict__ Z)
{
    __shared__ ushort lK[64 * 64];
    __shared__ ushort lV[64 * 64];
    __shared__ ushort lP[64 * 72];

    const int h = blockIdx.y;                 // b*12 + a
    const int q0 = blockIdx.x * 64;
    const ushort* Qh = (const ushort*)Q + (size_t)h * 32768;
    const ushort* Kh = (const ushort*)Kx + (size_t)h * 32768;
    const ushort* Vh = (const ushort*)Vt + (size_t)h * 32768;   // [64][512]
    const int* mk = mask + (h / 12) * 512;
    ushort* Zh = (ushort*)Z + (size_t)h * 32768;

    const int tid = threadIdx.x;
    const int l = tid & 63, w = tid >> 6;
    const int l16 = l & 15, quad = l >> 4;

    bf16x8 qfr[2];
#pragma unroll
    for (int kk = 0; kk < 2; ++kk)
        qfr[kk] = *(const bf16x8*)(Qh + (size_t)(q0 + w * 16 + l16) * 64 + kk * 32 + quad * 8);

    const int c8p = tid & 7;
    const int kr0 = tid >> 3;
    float m_i[4] = {-1e30f, -1e30f, -1e30f, -1e30f};
    float l_i[4] = {0.f, 0.f, 0.f, 0.f};
    f32x4 o4[4] = {};

    for (int kt = 0; kt < 8; ++kt) {
#pragma unroll
        for (int p = 0; p < 2; ++p) {
            int row = kr0 + p * 32;
            int c8l = c8p ^ (row & 7);
            glds16(Kh + (size_t)(kt * 64 + row) * 64 + c8l * 8, lK + (p * 256 + tid) * 8);
            glds16(Vh + (size_t)row * 512 + kt * 64 + c8l * 8, lV + (p * 256 + tid) * 8);
        }
        __syncthreads();

        f32x4 s4[4] = {};
#pragma unroll
        for (int kk = 0; kk < 2; ++kk) {
#pragma unroll
            for (int nt = 0; nt < 4; ++nt) {
                int rr = nt * 16 + l16;
                bf16x8 bfr = *(const bf16x8*)&lK[rr * 64 + (((kk * 4 + quad) ^ (l16 & 7)) << 3)];
                s4[nt] = __builtin_amdgcn_mfma_f32_16x16x32_bf16(qfr[kk], bfr, s4[nt], 0, 0, 0);
            }
        }

        bool mz[4];
#pragma unroll
        for (int nt = 0; nt < 4; ++nt) mz[nt] = (mk[kt * 64 + nt * 16 + l16] == 0);
        float pv[4][4];
#pragma unroll
        for (int r = 0; r < 4; ++r) {
            float rm = -1e30f;
#pragma unroll
            for (int nt = 0; nt < 4; ++nt) {
                float v = mz[nt] ? -1e30f : s4[nt][r] * 0.125f;
                pv[nt][r] = v;
                rm = fmaxf(rm, v);
            }
#pragma unroll
            for (int off = 1; off < 16; off <<= 1) rm = fmaxf(rm, __shfl_xor(rm, off));
            float mn = fmaxf(m_i[r], rm);
            float al = __expf(m_i[r] - mn);
            float rs = 0.f;
#pragma unroll
            for (int nt = 0; nt < 4; ++nt) {
                float e = __expf(pv[nt][r] - mn);
                pv[nt][r] = e;
                rs += e;
            }
#pragma unroll
            for (int off = 1; off < 16; off <<= 1) rs += __shfl_xor(rs, off);
            l_i[r] = l_i[r] * al + rs;
            m_i[r] = mn;
#pragma unroll
            for (int dt = 0; dt < 4; ++dt) o4[dt][r] *= al;
        }

#pragma unroll
        for (int nt = 0; nt < 4; ++nt)
#pragma unroll
            for (int r = 0; r < 4; ++r)
                lP[(w * 16 + quad * 4 + r) * 72 + nt * 16 + l16] = f2bu(pv[nt][r]);
        __syncthreads();

#pragma unroll
        for (int kk = 0; kk < 2; ++kk) {
            bf16x8 pafr = *(const bf16x8*)&lP[(w * 16 + l16) * 72 + kk * 32 + quad * 8];
#pragma unroll
            for (int dt = 0; dt < 4; ++dt) {
                bf16x8 bvfr = *(const bf16x8*)&lV[(dt * 16 + l16) * 64 + (((kk * 4 + quad) ^ (l16 & 7)) << 3)];
                o4[dt] = __builtin_amdgcn_mfma_f32_16x16x32_bf16(pafr, bvfr, o4[dt], 0, 0, 0);
            }
        }
        __syncthreads();
    }

    float inv[4];
#pragma unroll
    for (int r = 0; r < 4; ++r) inv[r] = 1.f / l_i[r];
#pragma unroll
    for (int dt = 0; dt < 4; ++dt)
#pragma unroll
        for (int r = 0; r < 4; ++r)
            Zh[(size_t)(q0 + w * 16 + quad * 4 + r) * 64 + dt * 16 + l16] = f2bu(o4[dt][r] * inv[r]);
}

// ---------------------------------------------------------------------------
// LayerNorm over H=768, one block per row, fp32 stats. In-place safe.
// ---------------------------------------------------------------------------
__device__ __forceinline__ float to_f(float v)  { return v; }
__device__ __forceinline__ float to_f(bf16_t v) { return b2f(v); }
__device__ __forceinline__ void from_f(float& d, float v)  { d = v; }
__device__ __forceinline__ void from_f(bf16_t& d, float v) { d = f2b(v); }

template <typename TI, typename TO>
__global__ __launch_bounds__(256) void layernorm_kernel(
    const TI* __restrict__ X, const float* __restrict__ w,
    const float* __restrict__ b, TO* __restrict__ out)
{
    const TI* x = X + (size_t)blockIdx.x * 768;
    TO* o = out + (size_t)blockIdx.x * 768;
    int t = threadIdx.x;
    float v[3];
    float s = 0.f, sq = 0.f;
#pragma unroll
    for (int i = 0; i < 3; ++i) {
        v[i] = to_f(x[t + i * 256]);
        s += v[i]; sq += v[i] * v[i];
    }
#pragma unroll
    for (int off = 32; off; off >>= 1) { s += __shfl_xor(s, off); sq += __shfl_xor(sq, off); }
    __shared__ float s1[4], s2[4];
    int wave = t >> 6, lane = t & 63;
    if (lane == 0) { s1[wave] = s; s2[wave] = sq; }
    __syncthreads();
    s  = s1[0] + s1[1] + s1[2] + s1[3];
    sq = s2[0] + s2[1] + s2[2] + s2[3];
    float mu  = s * (1.f / 768.f);
    float var = sq * (1.f / 768.f) - mu * mu;
    float rs  = rsqrtf(var + 1e-5f);
#pragma unroll
    for (int i = 0; i < 3; ++i)
        from_f(o[t + i * 256], (v[i] - mu) * rs * w[t + i * 256] + b[t + i * 256]);
}

// ---------------------------------------------------------------------------
extern "C" void kernel_launch(void* const* d_in, const int* in_sizes, int n_in,
                              void* d_out, int out_size, void* d_ws, size_t ws_size,
                              hipStream_t stream)
{
    const float* X    = (const float*)d_in[0];
    const int*   mask = (const int*)  d_in[1];
    const float* WQ   = (const float*)d_in[2];
    const float* bQ   = (const float*)d_in[3];
    const float* WK   = (const float*)d_in[4];
    const float* bK   = (const float*)d_in[5];
    const float* WV   = (const float*)d_in[6];
    const float* bV   = (const float*)d_in[7];
    const float* WO   = (const float*)d_in[8];
    const float* bO   = (const float*)d_in[9];
    const float* ln1w = (const float*)d_in[10];
    const float* ln1b = (const float*)d_in[11];
    const float* W1   = (const float*)d_in[12];
    const float* b1   = (const float*)d_in[13];
    const float* W2   = (const float*)d_in[14];
    const float* b2   = (const float*)d_in[15];
    const float* ln2w = (const float*)d_in[16];
    const float* ln2b = (const float*)d_in[17];
    float* out = (float*)d_out;

    // ---- workspace (bf16 elems; total 38,539,776 = 77.1 MB) ----
    bf16_t* ws   = (bf16_t*)d_ws;
    bf16_t* Wqkv = ws;                        // [2304][768] (WQt|WKt|WVt)
    bf16_t* WOt  = Wqkv + 1769472;            // [768][768]
    bf16_t* W1t  = WOt + 589824;              // [3072][768]
    bf16_t* W2t  = W1t + 2359296;             // [768][3072]
    float*  bcat = (float*)(W2t + 2359296);   // fp32[2304] (= 4608 bf16)
    bf16_t* Qb   = W2t + 2359296 + 4608;      // packed [8192][768]; MUST be Q,K,V consecutive (EPI 6)
    bf16_t* Kb   = Qb + 6291456;
    bf16_t* Vb   = Kb + 6291456;
    bf16_t* Xb   = Vb + 6291456;              // bf16 X (dead after QKV; Y1 alias)
    bf16_t* Vt   = Xb + 6291456;              // per-head V^T [192][64][512]
    // aliases (dead-before-write):
    bf16_t* Zb = Qb;   // flash writes Z in-place over Q
    bf16_t* Y1 = Xb;   // O-proj out (Xb dead after QKV gemm)
    bf16_t* X1 = Qb;   // LN1 out (Qb/Z dead after O-proj)
    bf16_t* Hb = Kb;   // FFN mid [8192][3072] = 25,165,824 = Kb+Vb+Xb+Vt exactly

    // ---- 1. prep: weight transposes + bias concat + X cast ----
    prep_kernel<<<4801, 256, 0, stream>>>(WQ, WK, WV, WO, W1, W2, bQ, bK, bV, X,
                                          Wqkv, WOt, W1t, W2t, bcat, Xb);

    // ---- 2. fused QKV projection (M=8192, N=2304, K=768) -> packed Q/K/V ----
    gemm128<6, 128><<<dim3(64, 18), 256, 0, stream>>>(Xb, Wqkv, bcat, nullptr, Qb,
                                                      768, 768, 768, 768);

    // ---- 3. per-head V transpose [512][64] -> [64][512], 192 heads ----
    transpose_bf<<<dim3(1, 8, 192), 256, 0, stream>>>((const ushort*)Vb, (ushort*)Vt,
                                                      512, 64, 32768, 32768);

    // ---- 4. flash attention, Z in-place over Q ----
    flash_kernel<<<dim3(8, 192), 256, 0, stream>>>(Qb, Kb, Vt, mask, Zb);

    // ---- 5. O-projection + fp32 residual -> Y1, LN1 -> X1 ----
    gemm128<2, 64><<<dim3(64, 12), 256, 0, stream>>>(Zb, WOt, bO, X, Y1,
                                                     768, 768, 768, 768);
    layernorm_kernel<bf16_t, bf16_t><<<8192, 256, 0, stream>>>(Y1, ln1w, ln1b, X1);

    // ---- 6. FFN: GELU(X1@W1+b1) -> Hb; Hb@W2+b2+X1 -> out (fp32); LN2 in-place ----
    gemm128<1, 128><<<dim3(64, 24), 256, 0, stream>>>(X1, W1t, b1, nullptr, Hb,
                                                      768, 768, 768, 3072);
    gemm128<5, 64><<<dim3(64, 12), 256, 0, stream>>>(Hb, W2t, b2, X1, out,
                                                     3072, 3072, 3072, 768);
    layernorm_kernel<float, float><<<8192, 256, 0, stream>>>(out, ln2w, ln2b, out);
}

// Round 6
// 369.979 us; speedup vs baseline: 1.7721x; 1.0655x over previous
//
#include <hip/hip_runtime.h>
#include <hip/hip_bf16.h>

// Encoder layer. fp32 in/out, bf16 MFMA compute, fp32 accum.
// B=16 S=512 H=768 A=12 DH=64 F=3072.
// Round 6: BK=64 K-loop (half the barriers, 32 MFMA/barrier, 32KB LDS) +
// tanh-form GELU (~12 VALU vs ~25 for erff; |err| ~1e-3 << threshold).
// Keeps: segmented-QKV gemm epilogue, packed per-head attention (faithful
// flat reshape), flash attention, prep mega-kernel.

using bf16_t = __hip_bfloat16;
typedef __bf16 bf16x8 __attribute__((ext_vector_type(8)));
typedef float f32x4 __attribute__((ext_vector_type(4)));

__device__ __forceinline__ float b2f(bf16_t v) { return __bfloat162float(v); }
__device__ __forceinline__ bf16_t f2b(float v) { return __float2bfloat16(v); }
__device__ __forceinline__ ushort f2bu(float v) { bf16_t b = f2b(v); return *(ushort*)&b; }

// async global->LDS 16B copy (dest = wave base + lane*16 by construction)
__device__ __forceinline__ void glds16(const ushort* g, ushort* l) {
    __builtin_amdgcn_global_load_lds(
        (const __attribute__((address_space(1))) unsigned int*)g,
        (__attribute__((address_space(3))) unsigned int*)l, 16, 0, 0);
}

// tanh-form GELU: 0.5x(1+tanh(0.79788456x(1+0.044715x^2))).
// tanh(y) = 1 - 2/(e^{2y}+1): overflow-safe (inf -> 1, 0 -> -1).
__device__ __forceinline__ float gelu_f(float x) {
    float x2 = x * x;
    float y2 = 1.5957691216057308f * x * fmaf(0.044715f, x2, 1.0f);  // 2*a*x*(1+b*x2)
    float e = __expf(y2);
    float t = 1.f - 2.f / (e + 1.f);
    return 0.5f * x * (1.f + t);
}

// ---------------------------------------------------------------------------
// Prep mega-kernel: 6 weight transposes (fp32 [R][C] -> bf16 [C][R]) + bias
// concat (bQ|bK|bV -> bcat fp32[2304]) + X cast. One launch.
// ---------------------------------------------------------------------------
__device__ __forceinline__ void tr_tile(const float* __restrict__ in,
                                        bf16_t* __restrict__ out,
                                        int R, int C, int tx, int ty,
                                        float (*t)[65], int tid)
{
    int r0 = ty * 64, c0 = tx * 64;
    int tr = tid >> 6, tc = tid & 63;
#pragma unroll 4
    for (int i = 0; i < 16; ++i) {
        int r = i * 4 + tr;
        t[r][tc] = in[(size_t)(r0 + r) * C + c0 + tc];
    }
    __syncthreads();
#pragma unroll 4
    for (int i = 0; i < 16; ++i) {
        int r = i * 4 + tr;
        out[(size_t)(c0 + r) * R + r0 + tc] = f2b(t[tc][r]);
    }
}

__global__ __launch_bounds__(256) void prep_kernel(
    const float* __restrict__ WQ, const float* __restrict__ WK,
    const float* __restrict__ WV, const float* __restrict__ WO,
    const float* __restrict__ W1, const float* __restrict__ W2,
    const float* __restrict__ bQ, const float* __restrict__ bK,
    const float* __restrict__ bV, const float* __restrict__ X,
    bf16_t* __restrict__ Wqkv, bf16_t* __restrict__ WOt,
    bf16_t* __restrict__ W1t, bf16_t* __restrict__ W2t,
    float* __restrict__ bcat, bf16_t* __restrict__ Xb)
{
    __shared__ float t[64][65];
    const int blk = blockIdx.x, tid = threadIdx.x;
    if (blk < 576) {                       // 768x768 transposes
        int m = blk / 144, tt = blk % 144;
        const float* in = (m == 0) ? WQ : (m == 1) ? WK : (m == 2) ? WV : WO;
        bf16_t* out = (m == 0) ? Wqkv : (m == 1) ? Wqkv + 589824
                    : (m == 2) ? Wqkv + 1179648 : WOt;
        tr_tile(in, out, 768, 768, tt % 12, tt / 12, t, tid);
    } else if (blk < 1152) {               // W1 [768][3072] -> [3072][768]
        int tt = blk - 576;
        tr_tile(W1, W1t, 768, 3072, tt % 48, tt / 48, t, tid);
    } else if (blk < 1728) {               // W2 [3072][768] -> [768][3072]
        int tt = blk - 1152;
        tr_tile(W2, W2t, 3072, 768, tt % 12, tt / 12, t, tid);
    } else if (blk == 1728) {              // bias concat
        for (int i = tid; i < 2304; i += 256)
            bcat[i] = (i < 768) ? bQ[i] : (i < 1536) ? bK[i - 768] : bV[i - 1536];
    } else {                               // X cast, 2048 elems/block
        size_t i = ((size_t)(blk - 1729) * 256 + tid) * 8;
        float4 a = *(const float4*)(X + i);
        float4 b = *(const float4*)(X + i + 4);
#pragma unroll
        for (int j = 0; j < 4; ++j) {
            Xb[i + j]     = f2b(((const float*)&a)[j]);
            Xb[i + 4 + j] = f2b(((const float*)&b)[j]);
        }
    }
}

// ---------------------------------------------------------------------------
// bf16 [R][C] -> bf16 [C][R] transpose, batched over z (per-head V, packed)
// ---------------------------------------------------------------------------
__global__ __launch_bounds__(256) void transpose_bf(
    const ushort* __restrict__ in, ushort* __restrict__ out,
    int R, int C, long inB, long outB)
{
    __shared__ ushort t[64][65];
    const ushort* ip = in + (size_t)blockIdx.z * inB;
    ushort* op = out + (size_t)blockIdx.z * outB;
    int r0 = blockIdx.y * 64, c0 = blockIdx.x * 64;
    int tr = threadIdx.x >> 6, tc = threadIdx.x & 63;
#pragma unroll 4
    for (int i = 0; i < 16; ++i) {
        int r = i * 4 + tr;
        t[r][tc] = ip[(size_t)(r0 + r) * C + c0 + tc];
    }
    __syncthreads();
#pragma unroll 4
    for (int i = 0; i < 16; ++i) {
        int r = i * 4 + tr;
        op[(size_t)(c0 + r) * R + r0 + tc] = t[tc][r];
    }
}

// ---------------------------------------------------------------------------
// NT GEMM, BK=64: C[M,N] = A[M,K] @ Bt[N,K]^T (+ epilogue).
// Tile 128 x NTILE x 64, 256 thr = 4 waves; 2 MFMA k-steps per iteration
// (32 MFMA/barrier at NTILE=128). LDS rows = 64 elems (128 B); staging swizzle
// applied on the GLOBAL side: thread t (row=t>>3, phys chunk=t&7) loads global
// chunk (t&7)^(row&7); frag reads use phys = (kk*4+quad)^(l16&7) -> 2 lanes
// per bank (free per m136). glds dest stays lane-ordered (HW requirement).
// EPI: 0 bias->bf16 | 1 bias+GELU->bf16 | 2 bias+res(fp32,ld=ldc)->bf16
//      5 bias+res(bf16,ld=ldc)->fp32 | 6 bias, segmented n/768 -> packed bufs
// ---------------------------------------------------------------------------
template <int EPI, int NTILE>
__global__ __launch_bounds__(256) void gemm128(
    const bf16_t* __restrict__ A, const bf16_t* __restrict__ Bt,
    const float* __restrict__ bias, const void* __restrict__ res,
    void* __restrict__ Cv, int K, int lda, int ldb, int ldc)
{
    __shared__ ushort lA[128 * 64];
    __shared__ ushort lB[NTILE * 64];
    constexpr int NI = NTILE / 32;
    const int tid = threadIdx.x;
    const int l = tid & 63, w = tid >> 6;
    const int l16 = l & 15, quad = l >> 4;
    const int m0 = blockIdx.x * 128, n0 = blockIdx.y * NTILE;

    const int srow = tid >> 3;                        // 0..31
    const int sg = (((tid & 7) ^ (srow & 7)) << 3);   // global chunk offset
    const ushort* gA = (const ushort*)A + (size_t)(m0 + srow) * lda + sg;
    const ushort* gB = (const ushort*)Bt + (size_t)(n0 + srow) * ldb + sg;
    ushort* dA = lA + tid * 8;
    ushort* dB = lB + tid * 8;

    f32x4 acc[4][NI] = {};
    const int arow = (w & 1) * 64;
    const int brow = (w >> 1) * (NTILE / 2);

    for (int k0 = 0; k0 < K; k0 += 64) {
        __syncthreads();
        glds16(gA + k0,                      dA);
        glds16(gA + k0 + (size_t)32 * lda,   dA + 2048);
        glds16(gA + k0 + (size_t)64 * lda,   dA + 4096);
        glds16(gA + k0 + (size_t)96 * lda,   dA + 6144);
        glds16(gB + k0,                      dB);
        glds16(gB + k0 + (size_t)32 * ldb,   dB + 2048);
        if constexpr (NTILE == 128) {
            glds16(gB + k0 + (size_t)64 * ldb, dB + 4096);
            glds16(gB + k0 + (size_t)96 * ldb, dB + 6144);
        }
        __syncthreads();
#pragma unroll
        for (int kk = 0; kk < 2; ++kk) {
            const int pc = (((kk * 4 + quad) ^ (l16 & 7)) << 3);
            bf16x8 bfr[NI];
#pragma unroll
            for (int ni = 0; ni < NI; ++ni)
                bfr[ni] = *(const bf16x8*)&lB[(brow + ni * 16 + l16) * 64 + pc];
#pragma unroll
            for (int mi = 0; mi < 4; ++mi) {
                bf16x8 afr = *(const bf16x8*)&lA[(arow + mi * 16 + l16) * 64 + pc];
#pragma unroll
                for (int ni = 0; ni < NI; ++ni)
                    acc[mi][ni] = __builtin_amdgcn_mfma_f32_16x16x32_bf16(afr, bfr[ni], acc[mi][ni], 0, 0, 0);
            }
        }
    }

    float bv[NI];
#pragma unroll
    for (int ni = 0; ni < NI; ++ni) bv[ni] = bias[n0 + brow + ni * 16 + l16];

    // EPI 6: each NTILE=128 n-tile lies wholly in one of Q/K/V (768 % 128 == 0);
    // rebase to the packed per-matrix buffer (faithful-reshape requirement).
    bf16_t* Cseg = nullptr;
    int nloc0 = 0;
    if constexpr (EPI == 6) {
        Cseg = (bf16_t*)Cv + (size_t)(n0 / 768) * 6291456;
        nloc0 = (n0 % 768) + brow;
    }

#pragma unroll
    for (int mi = 0; mi < 4; ++mi) {
#pragma unroll
        for (int ni = 0; ni < NI; ++ni) {
            int n = n0 + brow + ni * 16 + l16;
#pragma unroll
            for (int r = 0; r < 4; ++r) {
                int m = m0 + arow + mi * 16 + quad * 4 + r;
                float v = acc[mi][ni][r] + bv[ni];
                if constexpr (EPI == 1) {
                    v = gelu_f(v);
                } else if constexpr (EPI == 2) {
                    v += ((const float*)res)[(size_t)m * ldc + n];
                } else if constexpr (EPI == 5) {
                    v += b2f(((const bf16_t*)res)[(size_t)m * ldc + n]);
                }
                if constexpr (EPI == 5) {
                    ((float*)Cv)[(size_t)m * ldc + n] = v;
                } else if constexpr (EPI == 6) {
                    Cseg[(size_t)m * 768 + nloc0 + ni * 16 + l16] = f2b(v);
                } else {
                    ((bf16_t*)Cv)[(size_t)m * ldc + n] = f2b(v);
                }
            }
        }
    }
}

// ---------------------------------------------------------------------------
// Flash attention on PACKED per-matrix buffers: one block = (q-tile 64, head h).
// Head h = contiguous 32768-elem [512][64] slice (faithful flat reshape).
// S=512 D=64, 8 K-tiles; online softmax; P via padded LDS (C->A layout);
// V pre-transposed per head ([64][512]). Z in-place over Q.
// ---------------------------------------------------------------------------
__global__ __launch_bounds__(256) void flash_kernel(
    const bf16_t* __restrict__ Q, const bf16_t* __restrict__ Kx,
    const bf16_t* __restrict__ Vt, const int* __restrict__ mask,
    bf16_t* __restrict__ Z)
{
    __shared__ ushort lK[64 * 64];
    __shared__ ushort lV[64 * 64];
    __shared__ ushort lP[64 * 72];

    const int h = blockIdx.y;                 // b*12 + a
    const int q0 = blockIdx.x * 64;
    const ushort* Qh = (const ushort*)Q + (size_t)h * 32768;
    const ushort* Kh = (const ushort*)Kx + (size_t)h * 32768;
    const ushort* Vh = (const ushort*)Vt + (size_t)h * 32768;   // [64][512]
    const int* mk = mask + (h / 12) * 512;
    ushort* Zh = (ushort*)Z + (size_t)h * 32768;

    const int tid = threadIdx.x;
    const int l = tid & 63, w = tid >> 6;
    const int l16 = l & 15, quad = l >> 4;

    bf16x8 qfr[2];
#pragma unroll
    for (int kk = 0; kk < 2; ++kk)
        qfr[kk] = *(const bf16x8*)(Qh + (size_t)(q0 + w * 16 + l16) * 64 + kk * 32 + quad * 8);

    const int c8p = tid & 7;
    const int kr0 = tid >> 3;
    float m_i[4] = {-1e30f, -1e30f, -1e30f, -1e30f};
    float l_i[4] = {0.f, 0.f, 0.f, 0.f};
    f32x4 o4[4] = {};

    for (int kt = 0; kt < 8; ++kt) {
#pragma unroll
        for (int p = 0; p < 2; ++p) {
            int row = kr0 + p * 32;
            int c8l = c8p ^ (row & 7);
            glds16(Kh + (size_t)(kt * 64 + row) * 64 + c8l * 8, lK + (p * 256 + tid) * 8);
            glds16(Vh + (size_t)row * 512 + kt * 64 + c8l * 8, lV + (p * 256 + tid) * 8);
        }
        __syncthreads();

        f32x4 s4[4] = {};
#pragma unroll
        for (int kk = 0; kk < 2; ++kk) {
#pragma unroll
            for (int nt = 0; nt < 4; ++nt) {
                int rr = nt * 16 + l16;
                bf16x8 bfr = *(const bf16x8*)&lK[rr * 64 + (((kk * 4 + quad) ^ (l16 & 7)) << 3)];
                s4[nt] = __builtin_amdgcn_mfma_f32_16x16x32_bf16(qfr[kk], bfr, s4[nt], 0, 0, 0);
            }
        }

        bool mz[4];
#pragma unroll
        for (int nt = 0; nt < 4; ++nt) mz[nt] = (mk[kt * 64 + nt * 16 + l16] == 0);
        float pv[4][4];
#pragma unroll
        for (int r = 0; r < 4; ++r) {
            float rm = -1e30f;
#pragma unroll
            for (int nt = 0; nt < 4; ++nt) {
                float v = mz[nt] ? -1e30f : s4[nt][r] * 0.125f;
                pv[nt][r] = v;
                rm = fmaxf(rm, v);
            }
#pragma unroll
            for (int off = 1; off < 16; off <<= 1) rm = fmaxf(rm, __shfl_xor(rm, off));
            float mn = fmaxf(m_i[r], rm);
            float al = __expf(m_i[r] - mn);
            float rs = 0.f;
#pragma unroll
            for (int nt = 0; nt < 4; ++nt) {
                float e = __expf(pv[nt][r] - mn);
                pv[nt][r] = e;
                rs += e;
            }
#pragma unroll
            for (int off = 1; off < 16; off <<= 1) rs += __shfl_xor(rs, off);
            l_i[r] = l_i[r] * al + rs;
            m_i[r] = mn;
#pragma unroll
            for (int dt = 0; dt < 4; ++dt) o4[dt][r] *= al;
        }

#pragma unroll
        for (int nt = 0; nt < 4; ++nt)
#pragma unroll
            for (int r = 0; r < 4; ++r)
                lP[(w * 16 + quad * 4 + r) * 72 + nt * 16 + l16] = f2bu(pv[nt][r]);
        __syncthreads();

#pragma unroll
        for (int kk = 0; kk < 2; ++kk) {
            bf16x8 pafr = *(const bf16x8*)&lP[(w * 16 + l16) * 72 + kk * 32 + quad * 8];
#pragma unroll
            for (int dt = 0; dt < 4; ++dt) {
                bf16x8 bvfr = *(const bf16x8*)&lV[(dt * 16 + l16) * 64 + (((kk * 4 + quad) ^ (l16 & 7)) << 3)];
                o4[dt] = __builtin_amdgcn_mfma_f32_16x16x32_bf16(pafr, bvfr, o4[dt], 0, 0, 0);
            }
        }
        __syncthreads();
    }

    float inv[4];
#pragma unroll
    for (int r = 0; r < 4; ++r) inv[r] = 1.f / l_i[r];
#pragma unroll
    for (int dt = 0; dt < 4; ++dt)
#pragma unroll
        for (int r = 0; r < 4; ++r)
            Zh[(size_t)(q0 + w * 16 + quad * 4 + r) * 64 + dt * 16 + l16] = f2bu(o4[dt][r] * inv[r]);
}

// ---------------------------------------------------------------------------
// LayerNorm over H=768, one block per row, fp32 stats. In-place safe.
// ---------------------------------------------------------------------------
__device__ __forceinline__ float to_f(float v)  { return v; }
__device__ __forceinline__ float to_f(bf16_t v) { return b2f(v); }
__device__ __forceinline__ void from_f(float& d, float v)  { d = v; }
__device__ __forceinline__ void from_f(bf16_t& d, float v) { d = f2b(v); }

template <typename TI, typename TO>
__global__ __launch_bounds__(256) void layernorm_kernel(
    const TI* __restrict__ X, const float* __restrict__ w,
    const float* __restrict__ b, TO* __restrict__ out)
{
    const TI* x = X + (size_t)blockIdx.x * 768;
    TO* o = out + (size_t)blockIdx.x * 768;
    int t = threadIdx.x;
    float v[3];
    float s = 0.f, sq = 0.f;
#pragma unroll
    for (int i = 0; i < 3; ++i) {
        v[i] = to_f(x[t + i * 256]);
        s += v[i]; sq += v[i] * v[i];
    }
#pragma unroll
    for (int off = 32; off; off >>= 1) { s += __shfl_xor(s, off); sq += __shfl_xor(sq, off); }
    __shared__ float s1[4], s2[4];
    int wave = t >> 6, lane = t & 63;
    if (lane == 0) { s1[wave] = s; s2[wave] = sq; }
    __syncthreads();
    s  = s1[0] + s1[1] + s1[2] + s1[3];
    sq = s2[0] + s2[1] + s2[2] + s2[3];
    float mu  = s * (1.f / 768.f);
    float var = sq * (1.f / 768.f) - mu * mu;
    float rs  = rsqrtf(var + 1e-5f);
#pragma unroll
    for (int i = 0; i < 3; ++i)
        from_f(o[t + i * 256], (v[i] - mu) * rs * w[t + i * 256] + b[t + i * 256]);
}

// ---------------------------------------------------------------------------
extern "C" void kernel_launch(void* const* d_in, const int* in_sizes, int n_in,
                              void* d_out, int out_size, void* d_ws, size_t ws_size,
                              hipStream_t stream)
{
    const float* X    = (const float*)d_in[0];
    const int*   mask = (const int*)  d_in[1];
    const float* WQ   = (const float*)d_in[2];
    const float* bQ   = (const float*)d_in[3];
    const float* WK   = (const float*)d_in[4];
    const float* bK   = (const float*)d_in[5];
    const float* WV   = (const float*)d_in[6];
    const float* bV   = (const float*)d_in[7];
    const float* WO   = (const float*)d_in[8];
    const float* bO   = (const float*)d_in[9];
    const float* ln1w = (const float*)d_in[10];
    const float* ln1b = (const float*)d_in[11];
    const float* W1   = (const float*)d_in[12];
    const float* b1   = (const float*)d_in[13];
    const float* W2   = (const float*)d_in[14];
    const float* b2   = (const float*)d_in[15];
    const float* ln2w = (const float*)d_in[16];
    const float* ln2b = (const float*)d_in[17];
    float* out = (float*)d_out;

    // ---- workspace (bf16 elems; total 38,539,776 = 77.1 MB) ----
    bf16_t* ws   = (bf16_t*)d_ws;
    bf16_t* Wqkv = ws;                        // [2304][768] (WQt|WKt|WVt)
    bf16_t* WOt  = Wqkv + 1769472;            // [768][768]
    bf16_t* W1t  = WOt + 589824;              // [3072][768]
    bf16_t* W2t  = W1t + 2359296;             // [768][3072]
    float*  bcat = (float*)(W2t + 2359296);   // fp32[2304] (= 4608 bf16)
    bf16_t* Qb   = W2t + 2359296 + 4608;      // packed [8192][768]; Q,K,V consecutive (EPI 6)
    bf16_t* Kb   = Qb + 6291456;
    bf16_t* Vb   = Kb + 6291456;
    bf16_t* Xb   = Vb + 6291456;              // bf16 X (dead after QKV; Y1 alias)
    bf16_t* Vt   = Xb + 6291456;              // per-head V^T [192][64][512]
    // aliases (dead-before-write):
    bf16_t* Zb = Qb;   // flash writes Z in-place over Q
    bf16_t* Y1 = Xb;   // O-proj out (Xb dead after QKV gemm)
    bf16_t* X1 = Qb;   // LN1 out (Qb/Z dead after O-proj)
    bf16_t* Hb = Kb;   // FFN mid [8192][3072] = 25,165,824 = Kb+Vb+Xb+Vt exactly

    // ---- 1. prep: weight transposes + bias concat + X cast ----
    prep_kernel<<<4801, 256, 0, stream>>>(WQ, WK, WV, WO, W1, W2, bQ, bK, bV, X,
                                          Wqkv, WOt, W1t, W2t, bcat, Xb);

    // ---- 2. fused QKV projection (M=8192, N=2304, K=768) -> packed Q/K/V ----
    gemm128<6, 128><<<dim3(64, 18), 256, 0, stream>>>(Xb, Wqkv, bcat, nullptr, Qb,
                                                      768, 768, 768, 768);

    // ---- 3. per-head V transpose [512][64] -> [64][512], 192 heads ----
    transpose_bf<<<dim3(1, 8, 192), 256, 0, stream>>>((const ushort*)Vb, (ushort*)Vt,
                                                      512, 64, 32768, 32768);

    // ---- 4. flash attention, Z in-place over Q ----
    flash_kernel<<<dim3(8, 192), 256, 0, stream>>>(Qb, Kb, Vt, mask, Zb);

    // ---- 5. O-projection + fp32 residual -> Y1, LN1 -> X1 ----
    gemm128<2, 64><<<dim3(64, 12), 256, 0, stream>>>(Zb, WOt, bO, X, Y1,
                                                     768, 768, 768, 768);
    layernorm_kernel<bf16_t, bf16_t><<<8192, 256, 0, stream>>>(Y1, ln1w, ln1b, X1);

    // ---- 6. FFN: GELU(X1@W1+b1) -> Hb; Hb@W2+b2+X1 -> out (fp32); LN2 in-place ----
    gemm128<1, 128><<<dim3(64, 24), 256, 0, stream>>>(X1, W1t, b1, nullptr, Hb,
                                                      768, 768, 768, 3072);
    gemm128<5, 64><<<dim3(64, 12), 256, 0, stream>>>(Hb, W2t, b2, X1, out,
                                                     3072, 3072, 3072, 768);
    layernorm_kernel<float, float><<<8192, 256, 0, stream>>>(out, ln2w, ln2b, out);
}